// Round 18
// baseline (49.875 us; speedup 1.0000x reference)
//
#include <hip/hip_runtime.h>
#include <hip/hip_bf16.h>

// AdLIF SNN forward, MI355X. B=512, T=500, NIN=96, H=512, NOUT=2.
//
// Round-17 = round-10 (best: 50.06 us, VGPR=60, no spill) + LDS diet:
// the 24 KB cold-only Icold buffer now UNIONS with the hot x double-buffer
// (cold path never uses the dbuf; it identity-restages into buf0 and keeps
// I-tiles at +13.3 KB, PTC=20). Block LDS 55.8 -> ~38 KB => TWO 1024-thread
// blocks co-resident per CU (VGPR 60 fits the 64-reg cap at 8 waves/SIMD):
// all 512 blocks run in ONE round (was two serial rounds) and 32 waves/CU
// hide the fold/MFMA serial chains that left both pipes <30% busy.
// Register-cap lesson (r12-r16): >64 regs/wave in 1024-thread blocks is
// unbuildable on this toolchain -- this design needs none of that.
//
// Algorithm (validated r7-r16, absmax 4.9e-4):
// 1024 threads, 16 waves, wave owns 32 h (2 tiles). 64-step chunks, NPH=8,
// ONE barrier per phase.
//  - x staged in LDS bf16, TIME-PERMUTED rows (row s*16+4q+j holds
//    t_local=16q+4s+j): after 4 subtile MFMAs lane quad lq holds 16
//    consecutive timesteps per owned h.
//  - Fold: d = fma(al, d, acc) x16/segment + running max, in registers;
//    compose via shfl_xor(16/32) + al^16 chain at phase end.
//  - Spike spec: no spike => a==0,spk==0; trip = max_chain+|v_seg_start|>1
//    (sound). Flag -> rollback to LDS checkpoint, exact cold path
//    (identity restage, 16-step I tiles, full Wrec recurrence).
//  - Partial chunk 7 (52 steps): zero-fill + exact al^-12 correction.

#define B_ 512
#define T_ 500
#define NIN_ 96
#define H_ 512
#define CH 64
#define NPH 8
#define LASTN 52
#define XPAD 104        // shorts per x row (208 B pitch, 16B-aligned)
#define PTC 20          // cold-path I pitch (shorts, 40 B rows)
#define XBUF (CH * XPAD)            // shorts per x buffer (13,312 B)

typedef __attribute__((ext_vector_type(8))) short bf16x8;  // 8 bf16 = 4 VGPR
typedef __attribute__((ext_vector_type(4))) float f32x4;

__device__ __forceinline__ unsigned short f2bf(float f) {
    union { __hip_bfloat16 h; unsigned short s; } u;
    u.h = __float2bfloat16(f);
    return u.s;
}
__device__ __forceinline__ unsigned pk2(float lo, float hi) {
    return (unsigned)f2bf(lo) | ((unsigned)f2bf(hi) << 16);
}
__device__ __forceinline__ bf16x8 packw(const float* p, float om) {
    float4 u0 = *reinterpret_cast<const float4*>(p);
    float4 u1 = *reinterpret_cast<const float4*>(p + 4);
    union { unsigned d[4]; bf16x8 v8; } pk;
    pk.d[0] = pk2(om * u0.x, om * u0.y);
    pk.d[1] = pk2(om * u0.z, om * u0.w);
    pk.d[2] = pk2(om * u1.x, om * u1.y);
    pk.d[3] = pk2(om * u1.z, om * u1.w);
    return pk.v8;
}
__device__ __forceinline__ float pow16(float a) {
    float a2 = a * a, a4 = a2 * a2, a8 = a4 * a4;
    return a8 * a8;
}

// Exact AdLIF cold path. Irow holds I' = oma*I (bf16, oma folded in).
// Threads with active==0 participate in barriers only.
__device__ __noinline__ void exact_steps(
    int nsteps, const unsigned short* Irow, float* spk_lds,
    const float* __restrict__ Wrec, int tid, int active,
    float al, float oma, float rh, float be,
    float& v, float& a, float& spk)
{
    for (int tt = 0; tt < nsteps; ++tt) {
        if (active) {
            float Ip = __uint_as_float(((unsigned)Irow[tt]) << 16);
            float racc = 0.f;
            for (int hp = 0; hp < H_; ++hp) {
                if (spk_lds[hp] != 0.f) racc += Wrec[(size_t)tid * H_ + hp];
            }
            float vnew = (al * v) * (1.f - spk) + Ip + oma * (racc - a);
            spk = (vnew - 1.f) > 0.f ? 1.f : 0.f;
            a = fmaf(be, spk, rh * a);
            v = vnew;
        }
        __syncthreads();            // old spk fully read by everyone
        if (active) spk_lds[tid] = spk;
        __syncthreads();            // new spk visible
    }
}

__global__ __launch_bounds__(1024) void snn_lean(
    const float* __restrict__ x,      // [B, T, NIN]
    const float* __restrict__ W1,     // [H, NIN]
    const float* __restrict__ Wrec,   // [H, H]
    const float* __restrict__ W2,     // [2, H]
    const float* __restrict__ alpha,  // [H]
    const float* __restrict__ rho,    // [H]
    const float* __restrict__ beta_a, // [H]
    float* __restrict__ out)          // [B, 2]
{
    const int b    = blockIdx.x;
    const int tid  = threadIdx.x;
    const int wv   = tid >> 6;       // 0..15
    const int lane = tid & 63;
    const int lq   = lane >> 4;
    const int lr   = lane & 15;
    const int nact = (tid < H_);     // neuron-active (cold path / readout)

    // Union: hot = x dbuf [0, 2*XBUF) shorts; cold = identity x-stage in
    // buf0 [0, XBUF) + Icold at [XBUF, XBUF + H*PTC) (20,480 B, covers buf1).
    __shared__ __align__(16) unsigned short smem[2 * XBUF + 4096]; // 41.9 KB
    unsigned short* Icold = smem + XBUF;
    __shared__ float spk_lds[H_];
    __shared__ float vck_lds[H_];   // chunk-start v checkpoint, per neuron
    __shared__ int   flagLds[4];    // chunk j -> slot j&3
    __shared__ float red[32];

    // --- W1 fragments, NAMED, oma = 1-alpha folded in. Wave owns 2 h-tiles.
    bf16x8 wf00, wf01, wf02, wf10, wf11, wf12;
    float al0, al1, k0, k1;
#define LOADW(I, WA, WB, WC, ALV, KV) { \
    const int h_ = wv * 32 + (I) * 16 + lr; \
    const float av_ = alpha[h_]; ALV = av_; KV = pow16(av_); \
    const float om_ = 1.0f - av_; \
    const float* wr_ = W1 + h_ * NIN_ + lq * 8; \
    WA = packw(wr_, om_); WB = packw(wr_ + 32, om_); WC = packw(wr_ + 64, om_); }
    LOADW(0, wf00, wf01, wf02, al0, k0)
    LOADW(1, wf10, wf11, wf12, al1, k1)
#undef LOADW

    // x staging: 512 stagers (tid<512); thread covers t_local = st, 12 floats.
    const float4* xb4 = reinterpret_cast<const float4*>(x + (size_t)b * T_ * NIN_);
    const int stg = (tid < 512);
    const int st  = (tid >> 3) & 63; // row t within chunk (0..63)
    const int sq  = tid & 7;
    // time-permuted row: row s*16+4q+j holds t_local = 16q+4s+j
    const int rwPerm = ((st & 15) >> 2) * 16 + (st >> 4) * 4 + (st & 3);
    float4 xr0, xr1, xr2;
    auto XLOAD = [&](int c) {
        if (stg) {
            int t = c * CH + st;
            if (t < T_) {
                const float4* p = xb4 + t * 24 + sq * 3;
                xr0 = p[0]; xr1 = p[1]; xr2 = p[2];
            } else {
                xr0 = make_float4(0.f, 0.f, 0.f, 0.f);
                xr1 = xr0; xr2 = xr0;
            }
        }
    };
    auto XWRITE = [&](int buf, int row) {
        if (stg) {
            unsigned short* base = &smem[buf * XBUF + row * XPAD + sq * 12];
            *reinterpret_cast<uint2*>(base)     = make_uint2(pk2(xr0.x, xr0.y), pk2(xr0.z, xr0.w));
            *reinterpret_cast<uint2*>(base + 4) = make_uint2(pk2(xr1.x, xr1.y), pk2(xr1.z, xr1.w));
            *reinterpret_cast<uint2*>(base + 8) = make_uint2(pk2(xr2.x, xr2.y), pk2(xr2.z, xr2.w));
        }
    };

    float v0s = 0.f, v1s = 0.f;     // running v per owned tile
    if (tid < 4) flagLds[tid] = 0;
    if (nact) vck_lds[tid] = 0.f;
    XLOAD(0); XWRITE(0, rwPerm);
    XLOAD(1);
    __syncthreads();

    int coldF = -1;
    const bool bb0 = (lq & 1) != 0, bb1 = (lq & 2) != 0;

    for (int p = 0; p < NPH; ++p) {
        if (p >= 1 && flagLds[(p - 1) & 3] != 0) { coldF = p - 1; break; }
        if (tid == 0) flagLds[(p + 1) & 3] = 0;
        // chunk-p checkpoint -> LDS (replicated over lq; lq==0 writes)
        if (lq == 0) {
            vck_lds[wv * 32 + lr]      = v0s;
            vck_lds[wv * 32 + 16 + lr] = v1s;
        }

        // --- MFMA + in-register fold, all named values.
        float d0 = 0.f, d1 = 0.f;
        float m0 = -3.4e38f, m1 = -3.4e38f;
        const unsigned short* xb = &smem[(p & 1) * XBUF];
#define MFMA2_(XF, WA, WB) \
        a0 = __builtin_amdgcn_mfma_f32_16x16x32_bf16(XF, WA, a0, 0, 0, 0); \
        a1 = __builtin_amdgcn_mfma_f32_16x16x32_bf16(XF, WB, a1, 0, 0, 0);
#define FOLD_(AV, ALV, DV, MV) \
        DV = fmaf(ALV, DV, AV[0]); MV = fmaxf(MV, DV); \
        DV = fmaf(ALV, DV, AV[1]); MV = fmaxf(MV, DV); \
        DV = fmaf(ALV, DV, AV[2]); MV = fmaxf(MV, DV); \
        DV = fmaf(ALV, DV, AV[3]); MV = fmaxf(MV, DV);
#define SUBTILE(S) { \
        f32x4 a0 = {0.f,0.f,0.f,0.f}, a1 = a0; \
        { bf16x8 xf = *reinterpret_cast<const bf16x8*>( \
              &xb[((S) * 16 + lr) * XPAD +  0 + lq * 8]); \
          MFMA2_(xf, wf00, wf10) } \
        { bf16x8 xf = *reinterpret_cast<const bf16x8*>( \
              &xb[((S) * 16 + lr) * XPAD + 32 + lq * 8]); \
          MFMA2_(xf, wf01, wf11) } \
        { bf16x8 xf = *reinterpret_cast<const bf16x8*>( \
              &xb[((S) * 16 + lr) * XPAD + 64 + lq * 8]); \
          MFMA2_(xf, wf02, wf12) } \
        FOLD_(a0, al0, d0, m0) FOLD_(a1, al1, d1, m1) }
        SUBTILE(0) SUBTILE(1) SUBTILE(2) SUBTILE(3)
#undef SUBTILE
#undef FOLD_
#undef MFMA2_

        if (p + 1 < NPH) XWRITE((p + 1) & 1, rwPerm);
        if (p + 2 < NPH) XLOAD(p + 2);

        // --- cross-lane composition: segment composites -> chunk update.
        bool trip = false;
#define COMPOSE(DV, MV, ALV, KV, VV) { \
        float A_  = DV; \
        float B_v = __shfl_xor(A_, 16); \
        float C_v = __shfl_xor(A_, 32); \
        float D_v = __shfl_xor(B_v, 32); \
        float x0_ = bb0 ? B_v : A_;  float x1_ = bb0 ? A_  : B_v; \
        float x2_ = bb0 ? D_v : C_v; float x3_ = bb0 ? C_v : D_v; \
        float e0_ = bb1 ? x2_ : x0_; float e1_ = bb1 ? x3_ : x1_; \
        float e2_ = bb1 ? x0_ : x2_; float e3_ = bb1 ? x1_ : x3_; \
        float w1_ = fmaf(KV, VV, e0_);  float w2_ = fmaf(KV, w1_, e1_); \
        float w3_ = fmaf(KV, w2_, e2_); float w4_ = fmaf(KV, w3_, e3_); \
        float vs_ = (lq == 0) ? VV : (lq == 1) ? w1_ : (lq == 2) ? w2_ : w3_; \
        trip = trip || ((MV + fabsf(vs_)) > 1.0f); \
        if (p == NPH - 1) { float q2_ = ALV * ALV, q4_ = q2_ * q2_; \
                            w4_ = w4_ * (q4_ / KV); } \
        VV = w4_; }
        COMPOSE(d0, m0, al0, k0, v0s)
        COMPOSE(d1, m1, al1, k1, v1s)
#undef COMPOSE
        if (trip) flagLds[p & 3] = 1;   // benign race, all store 1
        __syncthreads();                // xlds[(p+1)&1] + vck + flag visible
    }
    if (coldF < 0 && flagLds[(NPH - 1) & 3] != 0) coldF = NPH - 1;

    bool ex = false;
    float vex = 0.f;
    if (coldF >= 0) {
        // rollback: v at start of chunk coldF (from LDS); a,spk provably 0.
        float vv = nact ? vck_lds[tid] : 0.f;
        float aa = 0.f, ss = 0.f;
        const float alc  = alpha[nact ? tid : 0];
        const float omac = 1.0f - alc;
        const float rhc  = rho[nact ? tid : 0];
        const float bec  = beta_a[nact ? tid : 0];
        if (nact) spk_lds[tid] = 0.f;
        #pragma unroll 1
        for (int jj = coldF; jj < NPH; ++jj) {
            __syncthreads();
            XLOAD(jj); XWRITE(0, st);      // IDENTITY rows into buf 0
            __syncthreads();
            int remain = (jj == NPH - 1) ? LASTN : CH;
            #pragma unroll 1
            for (int s = 0; s < 4 && remain > 0; ++s) {
                f32x4 c0 = {0.f,0.f,0.f,0.f}, c1 = c0;
                #pragma unroll
                for (int kb = 0; kb < 3; ++kb) {
                    bf16x8 xf = *reinterpret_cast<const bf16x8*>(
                        &smem[(s * 16 + lr) * XPAD + kb * 32 + lq * 8]);
                    if (kb == 0) {
                        c0 = __builtin_amdgcn_mfma_f32_16x16x32_bf16(xf, wf00, c0, 0, 0, 0);
                        c1 = __builtin_amdgcn_mfma_f32_16x16x32_bf16(xf, wf10, c1, 0, 0, 0);
                    } else if (kb == 1) {
                        c0 = __builtin_amdgcn_mfma_f32_16x16x32_bf16(xf, wf01, c0, 0, 0, 0);
                        c1 = __builtin_amdgcn_mfma_f32_16x16x32_bf16(xf, wf11, c1, 0, 0, 0);
                    } else {
                        c0 = __builtin_amdgcn_mfma_f32_16x16x32_bf16(xf, wf02, c0, 0, 0, 0);
                        c1 = __builtin_amdgcn_mfma_f32_16x16x32_bf16(xf, wf12, c1, 0, 0, 0);
                    }
                }
                const int h0 = wv * 32 + lr;
                *reinterpret_cast<uint2*>(&Icold[(h0     ) * PTC + lq * 4]) =
                    make_uint2(pk2(c0[0], c0[1]), pk2(c0[2], c0[3]));
                *reinterpret_cast<uint2*>(&Icold[(h0 + 16) * PTC + lq * 4]) =
                    make_uint2(pk2(c1[0], c1[1]), pk2(c1[2], c1[3]));
                __syncthreads();
                int ns = remain < 16 ? remain : 16;
                exact_steps(ns, &Icold[nact ? tid * PTC : 0], spk_lds, Wrec,
                            tid, nact, alc, omac, rhc, bec, vv, aa, ss);
                remain -= ns;
            }
        }
        vex = vv;
        ex = true;
    }

    // Readout: out[b,n] = sum_h v_h * W2[n,h]
    float p0 = 0.f, p1 = 0.f;
    if (ex) {
        if (nact) {
            p0 = vex * W2[tid];
            p1 = vex * W2[H_ + tid];
        }
    } else {
        if (lq == 0) {   // v replicated over lq; count each h once
            const int h0 = wv * 32 + lr;
            p0 = v0s * W2[h0]      + v1s * W2[h0 + 16];
            p1 = v0s * W2[H_ + h0] + v1s * W2[H_ + h0 + 16];
        }
    }
    #pragma unroll
    for (int off = 32; off > 0; off >>= 1) {
        p0 += __shfl_down(p0, off, 64);
        p1 += __shfl_down(p1, off, 64);
    }
    if (lane == 0) { red[wv * 2] = p0; red[wv * 2 + 1] = p1; }
    __syncthreads();
    if (tid == 0) {
        float s0 = 0.f, s1 = 0.f;
        #pragma unroll
        for (int w16 = 0; w16 < 16; ++w16) {
            s0 += red[w16 * 2]; s1 += red[w16 * 2 + 1];
        }
        out[b * 2 + 0] = s0;
        out[b * 2 + 1] = s1;
    }
}

extern "C" void kernel_launch(void* const* d_in, const int* in_sizes, int n_in,
                              void* d_out, int out_size, void* d_ws, size_t ws_size,
                              hipStream_t stream) {
    const float* x      = (const float*)d_in[0];
    const float* W1     = (const float*)d_in[1];
    const float* Wrec   = (const float*)d_in[2];
    const float* W2     = (const float*)d_in[3];
    const float* alpha  = (const float*)d_in[4];
    const float* rho    = (const float*)d_in[5];
    const float* beta_a = (const float*)d_in[6];
    float* out = (float*)d_out;

    snn_lean<<<dim3(B_), dim3(1024), 0, stream>>>(
        x, W1, Wrec, W2, alpha, rho, beta_a, out);
}

// Round 20
// 49.094 us; speedup vs baseline: 1.0159x; 1.0159x over previous
//
#include <hip/hip_runtime.h>
#include <hip/hip_bf16.h>

// AdLIF SNN forward, MI355X. B=512, T=500, NIN=96, H=512, NOUT=2.
//
// Round-20 = round-19 with the staging indexing bug FIXED:
// r19 moved to 1024 stagers x 6 shorts each (prefetch regs 12 -> 6) but
// kept the r18 write base sq*12 (valid for 512 stagers x 12 shorts).
// Result: odd 6-short slices of every x row never written (0xAA poison ->
// NaN bf16 into MFMA). Fix: base = sq*6, three dword stores (4B-aligned
// for all sq). Register shaves retained: no k0/k1 (al^16 recomputed at
// compose), merged running-max. Goal: arch VGPR <= 56 so VGPR+8 acc <= 64
// -> TWO 16-wave blocks per CU -> one serial block-round (tests the
// unified-register-file occupancy theory from r18/r19).
//
// Algorithm (validated r7-r18, absmax 4.9e-4): 1024 thr, 16 waves, wave
// owns 32 h (2 tiles). 64-step chunks, NPH=8, ONE barrier per phase.
// x staged in LDS bf16 TIME-PERMUTED (row s*16+4q+j holds t=16q+4s+j);
// fold d=fma(al,d,acc) x16/segment + running max in registers; compose
// via shfl_xor(16/32) + al^16 chain; spike spec with rollback-exact cold
// path (identity restage, I tiles in LDS union, full Wrec recurrence);
// partial chunk 7 zero-fill + al^-12 correction.

#define B_ 512
#define T_ 500
#define NIN_ 96
#define H_ 512
#define CH 64
#define NPH 8
#define LASTN 52
#define XPAD 104        // shorts per x row (208 B pitch, 16B-aligned)
#define PTC 20          // cold-path I pitch (shorts, 40 B rows)
#define XBUF (CH * XPAD)            // shorts per x buffer (13,312 B)

typedef __attribute__((ext_vector_type(8))) short bf16x8;  // 8 bf16 = 4 VGPR
typedef __attribute__((ext_vector_type(4))) float f32x4;

__device__ __forceinline__ unsigned short f2bf(float f) {
    union { __hip_bfloat16 h; unsigned short s; } u;
    u.h = __float2bfloat16(f);
    return u.s;
}
__device__ __forceinline__ unsigned pk2(float lo, float hi) {
    return (unsigned)f2bf(lo) | ((unsigned)f2bf(hi) << 16);
}
__device__ __forceinline__ bf16x8 packw(const float* p, float om) {
    float4 u0 = *reinterpret_cast<const float4*>(p);
    float4 u1 = *reinterpret_cast<const float4*>(p + 4);
    union { unsigned d[4]; bf16x8 v8; } pk;
    pk.d[0] = pk2(om * u0.x, om * u0.y);
    pk.d[1] = pk2(om * u0.z, om * u0.w);
    pk.d[2] = pk2(om * u1.x, om * u1.y);
    pk.d[3] = pk2(om * u1.z, om * u1.w);
    return pk.v8;
}
__device__ __forceinline__ float pow16(float a) {
    float a2 = a * a, a4 = a2 * a2, a8 = a4 * a4;
    return a8 * a8;
}

// Exact AdLIF cold path. Irow holds I' = oma*I (bf16, oma folded in).
// Threads with active==0 participate in barriers only.
__device__ __noinline__ void exact_steps(
    int nsteps, const unsigned short* Irow, float* spk_lds,
    const float* __restrict__ Wrec, int tid, int active,
    float al, float oma, float rh, float be,
    float& v, float& a, float& spk)
{
    for (int tt = 0; tt < nsteps; ++tt) {
        if (active) {
            float Ip = __uint_as_float(((unsigned)Irow[tt]) << 16);
            float racc = 0.f;
            for (int hp = 0; hp < H_; ++hp) {
                if (spk_lds[hp] != 0.f) racc += Wrec[(size_t)tid * H_ + hp];
            }
            float vnew = (al * v) * (1.f - spk) + Ip + oma * (racc - a);
            spk = (vnew - 1.f) > 0.f ? 1.f : 0.f;
            a = fmaf(be, spk, rh * a);
            v = vnew;
        }
        __syncthreads();            // old spk fully read by everyone
        if (active) spk_lds[tid] = spk;
        __syncthreads();            // new spk visible
    }
}

__global__ __launch_bounds__(1024) void snn_lean3(
    const float* __restrict__ x,      // [B, T, NIN]
    const float* __restrict__ W1,     // [H, NIN]
    const float* __restrict__ Wrec,   // [H, H]
    const float* __restrict__ W2,     // [2, H]
    const float* __restrict__ alpha,  // [H]
    const float* __restrict__ rho,    // [H]
    const float* __restrict__ beta_a, // [H]
    float* __restrict__ out)          // [B, 2]
{
    const int b    = blockIdx.x;
    const int tid  = threadIdx.x;
    const int wv   = tid >> 6;       // 0..15
    const int lane = tid & 63;
    const int lq   = lane >> 4;
    const int lr   = lane & 15;
    const int nact = (tid < H_);     // neuron-active (cold path / readout)

    // Union: hot = x dbuf [0, 2*XBUF) shorts; cold = identity x-stage in
    // buf0 [0, XBUF) + Icold at [XBUF, ...) (20,480 B, covers buf1).
    __shared__ __align__(16) unsigned short smem[2 * XBUF + 4096]; // 41.9 KB
    unsigned short* Icold = smem + XBUF;
    __shared__ float spk_lds[H_];
    __shared__ float vck_lds[H_];   // chunk-start v checkpoint, per neuron
    __shared__ int   flagLds[4];    // chunk j -> slot j&3
    __shared__ float red[32];

    // --- W1 fragments, NAMED, oma = 1-alpha folded in. Wave owns 2 h-tiles.
    bf16x8 wf00, wf01, wf02, wf10, wf11, wf12;
    float al0, al1;
#define LOADW(I, WA, WB, WC, ALV) { \
    const int h_ = wv * 32 + (I) * 16 + lr; \
    const float av_ = alpha[h_]; ALV = av_; \
    const float om_ = 1.0f - av_; \
    const float* wr_ = W1 + h_ * NIN_ + lq * 8; \
    WA = packw(wr_, om_); WB = packw(wr_ + 32, om_); WC = packw(wr_ + 64, om_); }
    LOADW(0, wf00, wf01, wf02, al0)
    LOADW(1, wf10, wf11, wf12, al1)
#undef LOADW

    // x staging: ALL 1024 threads; thread covers row st = tid>>4 (0..63),
    // floats [sq*6, sq*6+6) (sq = tid&15) via 3x dwordx2 -> 6 prefetch VGPRs.
    const float2* xb2 = reinterpret_cast<const float2*>(x + (size_t)b * T_ * NIN_);
    const int st = tid >> 4, sq = tid & 15;
    // time-permuted row: row s*16+4q+j holds t_local = 16q+4s+j
    const int rwPerm = ((st & 15) >> 2) * 16 + (st >> 4) * 4 + (st & 3);
    float2 xr0, xr1, xr2;
    auto XLOAD = [&](int c) {
        int t = c * CH + st;
        if (t < T_) {
            const float2* p = xb2 + t * 48 + sq * 3;
            xr0 = p[0]; xr1 = p[1]; xr2 = p[2];
        } else {
            xr0 = make_float2(0.f, 0.f); xr1 = xr0; xr2 = xr0;
        }
    };
    auto XWRITE = [&](int buf, int row) {
        // 6 bf16 at short offset sq*6 (byte offset sq*12: 4B-aligned for
        // all sq) -> three dword stores.
        unsigned short* base = &smem[buf * XBUF + row * XPAD + sq * 6];
        reinterpret_cast<unsigned*>(base)[0] = pk2(xr0.x, xr0.y);
        reinterpret_cast<unsigned*>(base + 2)[0] = pk2(xr1.x, xr1.y);
        reinterpret_cast<unsigned*>(base + 4)[0] = pk2(xr2.x, xr2.y);
    };

    float v0s = 0.f, v1s = 0.f;     // running v per owned tile
    if (tid < 4) flagLds[tid] = 0;
    if (nact) vck_lds[tid] = 0.f;
    XLOAD(0); XWRITE(0, rwPerm);
    XLOAD(1);
    __syncthreads();

    int coldF = -1;
    const bool bb0 = (lq & 1) != 0, bb1 = (lq & 2) != 0;

    for (int p = 0; p < NPH; ++p) {
        if (p >= 1 && flagLds[(p - 1) & 3] != 0) { coldF = p - 1; break; }
        if (tid == 0) flagLds[(p + 1) & 3] = 0;
        // chunk-p checkpoint -> LDS (replicated over lq; lq==0 writes)
        if (lq == 0) {
            vck_lds[wv * 32 + lr]      = v0s;
            vck_lds[wv * 32 + 16 + lr] = v1s;
        }

        // --- MFMA + in-register fold, all named values.
        float d0 = 0.f, d1 = 0.f;
        float m = -3.4e38f;
        const unsigned short* xb = &smem[(p & 1) * XBUF];
#define MFMA2_(XF, WA, WB) \
        a0 = __builtin_amdgcn_mfma_f32_16x16x32_bf16(XF, WA, a0, 0, 0, 0); \
        a1 = __builtin_amdgcn_mfma_f32_16x16x32_bf16(XF, WB, a1, 0, 0, 0);
#define FOLD_(AV, ALV, DV) \
        DV = fmaf(ALV, DV, AV[0]); m = fmaxf(m, DV); \
        DV = fmaf(ALV, DV, AV[1]); m = fmaxf(m, DV); \
        DV = fmaf(ALV, DV, AV[2]); m = fmaxf(m, DV); \
        DV = fmaf(ALV, DV, AV[3]); m = fmaxf(m, DV);
#define SUBTILE(S) { \
        f32x4 a0 = {0.f,0.f,0.f,0.f}, a1 = a0; \
        { bf16x8 xf = *reinterpret_cast<const bf16x8*>( \
              &xb[((S) * 16 + lr) * XPAD +  0 + lq * 8]); \
          MFMA2_(xf, wf00, wf10) } \
        { bf16x8 xf = *reinterpret_cast<const bf16x8*>( \
              &xb[((S) * 16 + lr) * XPAD + 32 + lq * 8]); \
          MFMA2_(xf, wf01, wf11) } \
        { bf16x8 xf = *reinterpret_cast<const bf16x8*>( \
              &xb[((S) * 16 + lr) * XPAD + 64 + lq * 8]); \
          MFMA2_(xf, wf02, wf12) } \
        FOLD_(a0, al0, d0) FOLD_(a1, al1, d1) }
        SUBTILE(0) SUBTILE(1) SUBTILE(2) SUBTILE(3)
#undef SUBTILE
#undef FOLD_
#undef MFMA2_

        if (p + 1 < NPH) XWRITE((p + 1) & 1, rwPerm);
        if (p + 2 < NPH) XLOAD(p + 2);

        // --- cross-lane composition: segment composites -> chunk update.
        float vsmax = 0.f;
#define COMPOSE(DV, ALV, VV) { \
        float KV_ = pow16(ALV); \
        float A_  = DV; \
        float B_v = __shfl_xor(A_, 16); \
        float C_v = __shfl_xor(A_, 32); \
        float D_v = __shfl_xor(B_v, 32); \
        float x0_ = bb0 ? B_v : A_;  float x1_ = bb0 ? A_  : B_v; \
        float x2_ = bb0 ? D_v : C_v; float x3_ = bb0 ? C_v : D_v; \
        float e0_ = bb1 ? x2_ : x0_; float e1_ = bb1 ? x3_ : x1_; \
        float e2_ = bb1 ? x0_ : x2_; float e3_ = bb1 ? x1_ : x3_; \
        float w1_ = fmaf(KV_, VV, e0_);  float w2_ = fmaf(KV_, w1_, e1_); \
        float w3_ = fmaf(KV_, w2_, e2_); float w4_ = fmaf(KV_, w3_, e3_); \
        float vs_ = (lq == 0) ? VV : (lq == 1) ? w1_ : (lq == 2) ? w2_ : w3_; \
        vsmax = fmaxf(vsmax, fabsf(vs_)); \
        if (p == NPH - 1) { float q2_ = ALV * ALV, q4_ = q2_ * q2_; \
                            w4_ = w4_ * (q4_ / KV_); } \
        VV = w4_; }
        COMPOSE(d0, al0, v0s)
        COMPOSE(d1, al1, v1s)
#undef COMPOSE
        if ((m + vsmax) > 1.0f) flagLds[p & 3] = 1;   // benign race
        __syncthreads();                // xlds[(p+1)&1] + vck + flag visible
    }
    if (coldF < 0 && flagLds[(NPH - 1) & 3] != 0) coldF = NPH - 1;

    bool ex = false;
    float vex = 0.f;
    if (coldF >= 0) {
        // rollback: v at start of chunk coldF (from LDS); a,spk provably 0.
        float vv = nact ? vck_lds[tid] : 0.f;
        float aa = 0.f, ss = 0.f;
        const float alc  = alpha[nact ? tid : 0];
        const float omac = 1.0f - alc;
        const float rhc  = rho[nact ? tid : 0];
        const float bec  = beta_a[nact ? tid : 0];
        if (nact) spk_lds[tid] = 0.f;
        #pragma unroll 1
        for (int jj = coldF; jj < NPH; ++jj) {
            __syncthreads();
            XLOAD(jj); XWRITE(0, st);      // IDENTITY rows into buf 0
            __syncthreads();
            int remain = (jj == NPH - 1) ? LASTN : CH;
            #pragma unroll 1
            for (int s = 0; s < 4 && remain > 0; ++s) {
                f32x4 c0 = {0.f,0.f,0.f,0.f}, c1 = c0;
                #pragma unroll
                for (int kb = 0; kb < 3; ++kb) {
                    bf16x8 xf = *reinterpret_cast<const bf16x8*>(
                        &smem[(s * 16 + lr) * XPAD + kb * 32 + lq * 8]);
                    if (kb == 0) {
                        c0 = __builtin_amdgcn_mfma_f32_16x16x32_bf16(xf, wf00, c0, 0, 0, 0);
                        c1 = __builtin_amdgcn_mfma_f32_16x16x32_bf16(xf, wf10, c1, 0, 0, 0);
                    } else if (kb == 1) {
                        c0 = __builtin_amdgcn_mfma_f32_16x16x32_bf16(xf, wf01, c0, 0, 0, 0);
                        c1 = __builtin_amdgcn_mfma_f32_16x16x32_bf16(xf, wf11, c1, 0, 0, 0);
                    } else {
                        c0 = __builtin_amdgcn_mfma_f32_16x16x32_bf16(xf, wf02, c0, 0, 0, 0);
                        c1 = __builtin_amdgcn_mfma_f32_16x16x32_bf16(xf, wf12, c1, 0, 0, 0);
                    }
                }
                const int h0 = wv * 32 + lr;
                *reinterpret_cast<uint2*>(&Icold[(h0     ) * PTC + lq * 4]) =
                    make_uint2(pk2(c0[0], c0[1]), pk2(c0[2], c0[3]));
                *reinterpret_cast<uint2*>(&Icold[(h0 + 16) * PTC + lq * 4]) =
                    make_uint2(pk2(c1[0], c1[1]), pk2(c1[2], c1[3]));
                __syncthreads();
                int ns = remain < 16 ? remain : 16;
                exact_steps(ns, &Icold[nact ? tid * PTC : 0], spk_lds, Wrec,
                            tid, nact, alc, omac, rhc, bec, vv, aa, ss);
                remain -= ns;
            }
        }
        vex = vv;
        ex = true;
    }

    // Readout: out[b,n] = sum_h v_h * W2[n,h]
    float p0 = 0.f, p1 = 0.f;
    if (ex) {
        if (nact) {
            p0 = vex * W2[tid];
            p1 = vex * W2[H_ + tid];
        }
    } else {
        if (lq == 0) {   // v replicated over lq; count each h once
            const int h0 = wv * 32 + lr;
            p0 = v0s * W2[h0]      + v1s * W2[h0 + 16];
            p1 = v0s * W2[H_ + h0] + v1s * W2[H_ + h0 + 16];
        }
    }
    #pragma unroll
    for (int off = 32; off > 0; off >>= 1) {
        p0 += __shfl_down(p0, off, 64);
        p1 += __shfl_down(p1, off, 64);
    }
    if (lane == 0) { red[wv * 2] = p0; red[wv * 2 + 1] = p1; }
    __syncthreads();
    if (tid == 0) {
        float s0 = 0.f, s1 = 0.f;
        #pragma unroll
        for (int w16 = 0; w16 < 16; ++w16) {
            s0 += red[w16 * 2]; s1 += red[w16 * 2 + 1];
        }
        out[b * 2 + 0] = s0;
        out[b * 2 + 1] = s1;
    }
}

extern "C" void kernel_launch(void* const* d_in, const int* in_sizes, int n_in,
                              void* d_out, int out_size, void* d_ws, size_t ws_size,
                              hipStream_t stream) {
    const float* x      = (const float*)d_in[0];
    const float* W1     = (const float*)d_in[1];
    const float* Wrec   = (const float*)d_in[2];
    const float* W2     = (const float*)d_in[3];
    const float* alpha  = (const float*)d_in[4];
    const float* rho    = (const float*)d_in[5];
    const float* beta_a = (const float*)d_in[6];
    float* out = (float*)d_out;

    snn_lean3<<<dim3(B_), dim3(1024), 0, stream>>>(
        x, W1, Wrec, W2, alpha, rho, beta_a, out);
}